// Round 2
// baseline (377.266 us; speedup 1.0000x reference)
//
#include <hip/hip_runtime.h>

// Problem constants (reference: B=32, L=1024, DG=1024, H=1024), all float32.
#define BB 32
#define LL 1024
#define DGG 1024
#define HH 1024

// gate[b,l] = sigmoid(sum_h query[b,h] * W[h,l] + bias[l])
// grid: (L/64, B), block: 256 = 4 h-groups x 64 lanes.
// Wave n handles h-group n for 64 consecutive l -> W row reads 256B coalesced.
__global__ __launch_bounds__(256) void gate_kernel(
    const float* __restrict__ query,  // [B,H]
    const float* __restrict__ W,      // [H,L]
    const float* __restrict__ bias,   // [L]
    float* __restrict__ gate)         // [B,L] (workspace)
{
    __shared__ float qs[HH];
    __shared__ float partial[4][64];

    const int b  = blockIdx.y;
    const int l0 = blockIdx.x * 64;
    const int t  = threadIdx.x;
    const int ll = t & 63;
    const int hg = t >> 6;            // 0..3, wave-uniform

    for (int h = t; h < HH; h += 256)
        qs[h] = query[b * HH + h];
    __syncthreads();

    const int l = l0 + ll;
    const float* Wp = W + (size_t)(hg * 256) * LL + l;
    float sum = 0.f;
    #pragma unroll 8
    for (int h = 0; h < 256; ++h)
        sum += qs[hg * 256 + h] * Wp[(size_t)h * LL];

    partial[hg][ll] = sum;
    __syncthreads();

    if (t < 64) {
        float s = partial[0][t] + partial[1][t] + partial[2][t] + partial[3][t]
                + bias[l0 + t];
        gate[b * LL + l0 + t] = 1.0f / (1.0f + __expf(-s));
    }
}

// out[b,l, 0:1024]    = gate[b,l] * graph[b,l,:]
// out[b,l, 1024:2048] = query[b,:]
// grid: B*L blocks, 256 threads. Each thread: one scaled float4 + one query float4.
__global__ __launch_bounds__(256) void out_kernel(
    const float* __restrict__ graph,  // [B,L,DG]
    const float* __restrict__ query,  // [B,H]
    const float* __restrict__ gate,   // [B,L]
    float* __restrict__ out)          // [B,L,DG+H]
{
    const int bl = blockIdx.x;        // b*L + l
    const int b  = bl >> 10;
    const int t  = threadIdx.x;
    const float g = gate[bl];

    const float4* gsrc = reinterpret_cast<const float4*>(graph) + (size_t)bl * 256; // 1024 f32 = 256 x float4
    const float4* qsrc = reinterpret_cast<const float4*>(query) + (size_t)b  * 256;
    float4*       dst  = reinterpret_cast<float4*>(out)         + (size_t)bl * 512; // 2048 f32 = 512 x float4

    float4 v = gsrc[t];
    float4 r = make_float4(v.x * g, v.y * g, v.z * g, v.w * g);
    dst[t] = r;
    dst[256 + t] = qsrc[t];
}

extern "C" void kernel_launch(void* const* d_in, const int* in_sizes, int n_in,
                              void* d_out, int out_size, void* d_ws, size_t ws_size,
                              hipStream_t stream) {
    const float* graph = (const float*)d_in[0]; // [B,L,DG]
    const float* query = (const float*)d_in[1]; // [B,H]
    const float* W     = (const float*)d_in[2]; // [H,L]
    const float* bias  = (const float*)d_in[3]; // [L]
    float* out  = (float*)d_out;
    float* gate = (float*)d_ws;   // B*L f32 = 128 KB scratch

    dim3 g1(LL / 64, BB);
    gate_kernel<<<g1, 256, 0, stream>>>(query, W, bias, gate);
    out_kernel<<<BB * LL, 256, 0, stream>>>(graph, query, gate, out);
}